// Round 1
// baseline (604.793 us; speedup 1.0000x reference)
//
#include <hip/hip_runtime.h>

#define D 128   // feature dim
#define H 64    // hidden dim of classifier

// ---------- CSR construction ----------

static __global__ void hist_k(const int* __restrict__ ei, int E, int* __restrict__ cnt) {
    int e = blockIdx.x * blockDim.x + threadIdx.x;
    if (e < E) atomicAdd(&cnt[ei[E + e]], 1);   // dst row of edge_index
}

static __global__ void dinv_k(const int* __restrict__ cnt, float* __restrict__ dinv, int n) {
    int i = blockIdx.x * blockDim.x + threadIdx.x;
    if (i < n) dinv[i] = rsqrtf((float)cnt[i] + 1.0f);   // +1 for self loop; deg >= 1 always
}

static __global__ void scanA_k(const int* __restrict__ cnt, int n, int* __restrict__ bsum) {
    __shared__ int s[256];
    int i = blockIdx.x * 256 + threadIdx.x;
    s[threadIdx.x] = (i < n) ? cnt[i] : 0;
    __syncthreads();
    for (int off = 128; off > 0; off >>= 1) {
        if ((int)threadIdx.x < off) s[threadIdx.x] += s[threadIdx.x + off];
        __syncthreads();
    }
    if (threadIdx.x == 0) bsum[blockIdx.x] = s[0];
}

static __global__ void scanB_k(int* __restrict__ bsum, int nb) {
    if (threadIdx.x == 0 && blockIdx.x == 0) {
        int run = 0;
        for (int i = 0; i < nb; i++) { int t = bsum[i]; bsum[i] = run; run += t; }
    }
}

static __global__ void scanC_k(const int* __restrict__ cnt, int n, const int* __restrict__ bsum,
                               int* __restrict__ rowptr) {
    __shared__ int s[256];
    int i = blockIdx.x * 256 + threadIdx.x;
    int v = (i < n) ? cnt[i] : 0;
    s[threadIdx.x] = v;
    __syncthreads();
    for (int off = 1; off < 256; off <<= 1) {       // inclusive Hillis-Steele
        int t = ((int)threadIdx.x >= off) ? s[threadIdx.x - off] : 0;
        __syncthreads();
        s[threadIdx.x] += t;
        __syncthreads();
    }
    if (i < n) {
        int excl = bsum[blockIdx.x] + s[threadIdx.x] - v;
        rowptr[i] = excl;
        if (i == n - 1) rowptr[n] = excl + v;
    }
}

static __global__ void fill_k(const int* __restrict__ ei, int E, const int* __restrict__ rowptr,
                              int* __restrict__ cursor, int* __restrict__ csr_src) {
    int e = blockIdx.x * blockDim.x + threadIdx.x;
    if (e < E) {
        int s = ei[e];
        int d = ei[E + e];
        int p = atomicAdd(&cursor[d], 1);
        csr_src[rowptr[d] + p] = s;
    }
}

// ---------- GEMM: h = x @ W  (x: n x 128, W: 128 x 128) ----------
// 16 rows/block, 256 threads. W fully staged in LDS (64 KB), x tile 8 KB.
// Each thread: 2 rows x 4 cols, fp32 FMA. n=50000 -> 3125 blocks.

static __global__ __launch_bounds__(256) void gemm_k(const float* __restrict__ x,
                                                     const float* __restrict__ W,
                                                     float* __restrict__ h, int n) {
    __shared__ float Ws[D * D];
    __shared__ float xs[16][D];
    const int tid = threadIdx.x;
    for (int i = tid; i < D * D / 4; i += 256)
        ((float4*)Ws)[i] = ((const float4*)W)[i];
    const int row0 = blockIdx.x * 16;
    for (int i = tid; i < 16 * (D / 4); i += 256) {
        int r = i / (D / 4), c = i % (D / 4);
        int gr = row0 + r;
        ((float4*)&xs[r][0])[c] = (gr < n) ? ((const float4*)&x[(size_t)gr * D])[c]
                                           : make_float4(0.f, 0.f, 0.f, 0.f);
    }
    __syncthreads();
    const int tx = tid & 31;       // col group: cols 4*tx .. 4*tx+3
    const int ty = tid >> 5;       // 0..7 -> rows 2*ty, 2*ty+1
    float acc0[4] = {0.f, 0.f, 0.f, 0.f};
    float acc1[4] = {0.f, 0.f, 0.f, 0.f};
    const int r0 = ty * 2, r1 = ty * 2 + 1;
    for (int k = 0; k < D; k++) {
        float4 w = *(const float4*)&Ws[k * D + tx * 4];
        float xa = xs[r0][k];
        float xb = xs[r1][k];
        acc0[0] = fmaf(xa, w.x, acc0[0]); acc0[1] = fmaf(xa, w.y, acc0[1]);
        acc0[2] = fmaf(xa, w.z, acc0[2]); acc0[3] = fmaf(xa, w.w, acc0[3]);
        acc1[0] = fmaf(xb, w.x, acc1[0]); acc1[1] = fmaf(xb, w.y, acc1[1]);
        acc1[2] = fmaf(xb, w.z, acc1[2]); acc1[3] = fmaf(xb, w.w, acc1[3]);
    }
    int gr0 = row0 + r0, gr1 = row0 + r1;
    if (gr0 < n) *(float4*)&h[(size_t)gr0 * D + tx * 4] = make_float4(acc0[0], acc0[1], acc0[2], acc0[3]);
    if (gr1 < n) *(float4*)&h[(size_t)gr1 * D + tx * 4] = make_float4(acc1[0], acc1[1], acc1[2], acc1[3]);
}

// ---------- Aggregation + bias + relu ----------
// out[d] = relu( dinv[d] * sum_{e->d} dinv[s]*h[s] + dinv[d]^2 * h[d] + b )
// 1 wave per node, 64 lanes x float2 = coalesced 512B gather per edge.

static __global__ __launch_bounds__(256) void agg_k(const float* __restrict__ h,
                                                    const float* __restrict__ dinv,
                                                    const int* __restrict__ rowptr,
                                                    const int* __restrict__ csr,
                                                    const float* __restrict__ b,
                                                    float* __restrict__ out, int n) {
    int node = blockIdx.x * 4 + (threadIdx.x >> 6);
    if (node >= n) return;
    int lane = threadIdx.x & 63;
    int f = lane * 2;
    int beg = rowptr[node], end = rowptr[node + 1];
    float ax = 0.f, ay = 0.f;
    int e = beg;
    for (; e + 1 < end; e += 2) {          // 2-edge unroll for load ILP
        int s0 = csr[e], s1 = csr[e + 1];
        float d0 = dinv[s0], d1 = dinv[s1];
        float2 v0 = *(const float2*)&h[(size_t)s0 * D + f];
        float2 v1 = *(const float2*)&h[(size_t)s1 * D + f];
        ax = fmaf(d0, v0.x, ax); ay = fmaf(d0, v0.y, ay);
        ax = fmaf(d1, v1.x, ax); ay = fmaf(d1, v1.y, ay);
    }
    if (e < end) {
        int s0 = csr[e];
        float d0 = dinv[s0];
        float2 v0 = *(const float2*)&h[(size_t)s0 * D + f];
        ax = fmaf(d0, v0.x, ax); ay = fmaf(d0, v0.y, ay);
    }
    float di = dinv[node];
    float2 hv = *(const float2*)&h[(size_t)node * D + f];
    float2 bb = *(const float2*)&b[f];
    float ox = fmaf(di, ax, di * di * hv.x) + bb.x;
    float oy = fmaf(di, ay, di * di * hv.y) + bb.y;
    *(float2*)&out[(size_t)node * D + f] = make_float2(fmaxf(ox, 0.f), fmaxf(oy, 0.f));
}

// ---------- Global mean pool (batch is sorted) ----------

static __global__ __launch_bounds__(128) void pool_k(const float* __restrict__ x,
                                                     const int* __restrict__ batch, int n,
                                                     float* __restrict__ pooled) {
    int g = blockIdx.x;
    int f = threadIdx.x;
    // lower_bound(batch, g) and lower_bound(batch, g+1); all threads do identical search
    int lo = 0, hi = n;
    while (lo < hi) { int m = (lo + hi) >> 1; if (batch[m] < g) lo = m + 1; else hi = m; }
    int start = lo;
    hi = n;
    while (lo < hi) { int m = (lo + hi) >> 1; if (batch[m] < g + 1) lo = m + 1; else hi = m; }
    int end = lo;
    float s = 0.f;
    for (int r = start; r < end; r++) s += x[(size_t)r * D + f];
    float c = (float)(end - start);
    pooled[(size_t)g * D + f] = s / fmaxf(c, 1.0f);
}

// ---------- Classifier: out = relu(pooled@Wc + bc) @ Wo + bo ----------

static __global__ __launch_bounds__(64) void cls_k(const float* __restrict__ pooled,
                                                   const float* __restrict__ Wc,
                                                   const float* __restrict__ bc,
                                                   const float* __restrict__ Wo,
                                                   const float* __restrict__ bo,
                                                   float* __restrict__ out) {
    int g = blockIdx.x;
    int t = threadIdx.x;   // 0..63 -> hidden unit
    __shared__ float p[D];
    p[t] = pooled[(size_t)g * D + t];
    p[t + 64] = pooled[(size_t)g * D + 64 + t];
    __syncthreads();
    float z = bc[t];
    for (int k = 0; k < D; k++) z = fmaf(p[k], Wc[k * H + t], z);
    z = fmaxf(z, 0.f);
    float v = z * Wo[t];
    for (int off = 32; off > 0; off >>= 1) v += __shfl_down(v, off);
    if (t == 0) out[g] = v + bo[0];
}

// ---------- Orchestration ----------

extern "C" void kernel_launch(void* const* d_in, const int* in_sizes, int n_in,
                              void* d_out, int out_size, void* d_ws, size_t ws_size,
                              hipStream_t stream) {
    const float* x     = (const float*)d_in[0];
    const int*   ei    = (const int*)d_in[1];
    const int*   batch = (const int*)d_in[2];
    const float* W1 = (const float*)d_in[3];
    const float* b1 = (const float*)d_in[4];
    const float* W2 = (const float*)d_in[5];
    const float* b2 = (const float*)d_in[6];
    const float* W3 = (const float*)d_in[7];
    const float* b3 = (const float*)d_in[8];
    const float* Wc = (const float*)d_in[9];
    const float* bc = (const float*)d_in[10];
    const float* Wo = (const float*)d_in[11];
    const float* bo = (const float*)d_in[12];

    const int n = in_sizes[0] / D;
    const int E = in_sizes[1] / 2;
    const int G = out_size;

    char* ws = (char*)d_ws;
    size_t off = 0;
    auto alloc = [&](size_t bytes) -> void* {
        void* p = ws + off;
        off = (off + bytes + 255) & ~(size_t)255;
        return p;
    };
    int*   cnt     = (int*)alloc((size_t)n * 4);
    int*   cursor  = (int*)alloc((size_t)n * 4);
    int*   rowptr  = (int*)alloc((size_t)(n + 1) * 4);
    int*   bsum    = (int*)alloc(1024);
    float* dinv    = (float*)alloc((size_t)n * 4);
    int*   csr_src = (int*)alloc((size_t)E * 4);
    float* hbuf    = (float*)alloc((size_t)n * D * 4);
    float* xbuf    = (float*)alloc((size_t)n * D * 4);
    float* pooled  = (float*)alloc((size_t)G * D * 4);
    (void)ws_size; (void)n_in;

    hipMemsetAsync(cnt, 0, (size_t)n * 4, stream);
    hipMemsetAsync(cursor, 0, (size_t)n * 4, stream);

    const int TB = 256;
    const int nb = (n + 255) / 256;

    hist_k<<<(E + TB - 1) / TB, TB, 0, stream>>>(ei, E, cnt);
    dinv_k<<<(n + TB - 1) / TB, TB, 0, stream>>>(cnt, dinv, n);
    scanA_k<<<nb, 256, 0, stream>>>(cnt, n, bsum);
    scanB_k<<<1, 64, 0, stream>>>(bsum, nb);
    scanC_k<<<nb, 256, 0, stream>>>(cnt, n, bsum, rowptr);
    fill_k<<<(E + TB - 1) / TB, TB, 0, stream>>>(ei, E, rowptr, cursor, csr_src);

    const int gemm_blocks = (n + 15) / 16;
    const int agg_blocks  = (n + 3) / 4;

    // layer 1
    gemm_k<<<gemm_blocks, 256, 0, stream>>>(x, W1, hbuf, n);
    agg_k<<<agg_blocks, 256, 0, stream>>>(hbuf, dinv, rowptr, csr_src, b1, xbuf, n);
    // layer 2
    gemm_k<<<gemm_blocks, 256, 0, stream>>>(xbuf, W2, hbuf, n);
    agg_k<<<agg_blocks, 256, 0, stream>>>(hbuf, dinv, rowptr, csr_src, b2, xbuf, n);
    // layer 3
    gemm_k<<<gemm_blocks, 256, 0, stream>>>(xbuf, W3, hbuf, n);
    agg_k<<<agg_blocks, 256, 0, stream>>>(hbuf, dinv, rowptr, csr_src, b3, xbuf, n);

    pool_k<<<G, 128, 0, stream>>>(xbuf, batch, n, pooled);
    cls_k<<<G, 64, 0, stream>>>(pooled, Wc, bc, Wo, bo, (float*)d_out);
}

// Round 2
// 465.661 us; speedup vs baseline: 1.2988x; 1.2988x over previous
//
#include <hip/hip_runtime.h>

#define D 128   // feature dim
#define H 64    // hidden dim of classifier

// ---------- bf16 helpers (bit-level, RNE) ----------

__device__ __forceinline__ unsigned int bf16_rne(float f) {
    unsigned int u = __float_as_uint(f);
    u += 0x7fffu + ((u >> 16) & 1u);
    return u >> 16;
}
__device__ __forceinline__ unsigned int pack_bf16(float a, float b) {
    return bf16_rne(a) | (bf16_rne(b) << 16);
}
__device__ __forceinline__ float bf16_lo(unsigned int u) { return __uint_as_float(u << 16); }
__device__ __forceinline__ float bf16_hi(unsigned int u) { return __uint_as_float(u & 0xffff0000u); }

// ---------- CSR construction ----------

static __global__ void hist_k(const int* __restrict__ ei, int E, int* __restrict__ cnt) {
    int e = blockIdx.x * blockDim.x + threadIdx.x;
    if (e < E) atomicAdd(&cnt[ei[E + e]], 1);   // dst row of edge_index
}

static __global__ void dinv_k(const int* __restrict__ cnt, float* __restrict__ dinv, int n) {
    int i = blockIdx.x * blockDim.x + threadIdx.x;
    if (i < n) dinv[i] = rsqrtf((float)cnt[i] + 1.0f);   // +1 for self loop; deg >= 1 always
}

static __global__ void scanA_k(const int* __restrict__ cnt, int n, int* __restrict__ bsum) {
    __shared__ int s[256];
    int i = blockIdx.x * 256 + threadIdx.x;
    s[threadIdx.x] = (i < n) ? cnt[i] : 0;
    __syncthreads();
    for (int off = 128; off > 0; off >>= 1) {
        if ((int)threadIdx.x < off) s[threadIdx.x] += s[threadIdx.x + off];
        __syncthreads();
    }
    if (threadIdx.x == 0) bsum[blockIdx.x] = s[0];
}

static __global__ void scanB_k(int* __restrict__ bsum, int nb) {
    if (threadIdx.x == 0 && blockIdx.x == 0) {
        int run = 0;
        for (int i = 0; i < nb; i++) { int t = bsum[i]; bsum[i] = run; run += t; }
    }
}

static __global__ void scanC_k(const int* __restrict__ cnt, int n, const int* __restrict__ bsum,
                               int* __restrict__ rowptr) {
    __shared__ int s[256];
    int i = blockIdx.x * 256 + threadIdx.x;
    int v = (i < n) ? cnt[i] : 0;
    s[threadIdx.x] = v;
    __syncthreads();
    for (int off = 1; off < 256; off <<= 1) {       // inclusive Hillis-Steele
        int t = ((int)threadIdx.x >= off) ? s[threadIdx.x - off] : 0;
        __syncthreads();
        s[threadIdx.x] += t;
        __syncthreads();
    }
    if (i < n) {
        int excl = bsum[blockIdx.x] + s[threadIdx.x] - v;
        rowptr[i] = excl;
        if (i == n - 1) rowptr[n] = excl + v;
    }
}

static __global__ void fill_k(const int* __restrict__ ei, int E, const int* __restrict__ rowptr,
                              int* __restrict__ cursor, int* __restrict__ csr_src) {
    int e = blockIdx.x * blockDim.x + threadIdx.x;
    if (e < E) {
        int s = ei[e];
        int d = ei[E + e];
        int p = atomicAdd(&cursor[d], 1);
        csr_src[rowptr[d] + p] = s;
    }
}

// ---------- GEMM: h_bf16 = bf16(x @ W)  (x: n x 128 fp32, W: 128 x 128 fp32) ----------
// 32 rows/block, 256 threads. W fully in LDS (64 KB) + x tile (16 KB) = 80 KB -> 2 blocks/CU.
// Thread = 4 rows x 4 cols; k stepped by 4 with float4 LDS reads only (2 LDS instr/k).
// Output packed bf16 (2 feats/uint) for the bandwidth-bound aggregation gather.

static __global__ __launch_bounds__(256) void gemm_k(const float* __restrict__ x,
                                                     const float* __restrict__ W,
                                                     unsigned int* __restrict__ hb, int n) {
    __shared__ float Ws[D * D];        // 64 KB
    __shared__ float xs[32 * D];       // 16 KB
    const int tid = threadIdx.x;
    for (int i = tid; i < D * D / 4; i += 256)
        ((float4*)Ws)[i] = ((const float4*)W)[i];
    const int row0 = blockIdx.x * 32;
    for (int i = tid; i < 32 * (D / 4); i += 256) {
        int r = i >> 5, c = i & 31;
        int gr = row0 + r;
        ((float4*)xs)[i] = (gr < n) ? ((const float4*)&x[(size_t)gr * D])[c]
                                    : make_float4(0.f, 0.f, 0.f, 0.f);
    }
    __syncthreads();
    const int tx = tid & 31;       // cols 4*tx .. 4*tx+3
    const int ty = tid >> 5;       // rows 4*ty .. 4*ty+3
    const int r0 = ty * 4;
    float acc[4][4];
#pragma unroll
    for (int r = 0; r < 4; r++)
#pragma unroll
        for (int c = 0; c < 4; c++) acc[r][c] = 0.f;

    for (int k = 0; k < D; k += 4) {
        float4 w0 = *(const float4*)&Ws[(k + 0) * D + tx * 4];
        float4 w1 = *(const float4*)&Ws[(k + 1) * D + tx * 4];
        float4 w2 = *(const float4*)&Ws[(k + 2) * D + tx * 4];
        float4 w3 = *(const float4*)&Ws[(k + 3) * D + tx * 4];
#pragma unroll
        for (int r = 0; r < 4; r++) {
            float4 xv = *(const float4*)&xs[(r0 + r) * D + k];
            acc[r][0] = fmaf(xv.x, w0.x, acc[r][0]);
            acc[r][1] = fmaf(xv.x, w0.y, acc[r][1]);
            acc[r][2] = fmaf(xv.x, w0.z, acc[r][2]);
            acc[r][3] = fmaf(xv.x, w0.w, acc[r][3]);
            acc[r][0] = fmaf(xv.y, w1.x, acc[r][0]);
            acc[r][1] = fmaf(xv.y, w1.y, acc[r][1]);
            acc[r][2] = fmaf(xv.y, w1.z, acc[r][2]);
            acc[r][3] = fmaf(xv.y, w1.w, acc[r][3]);
            acc[r][0] = fmaf(xv.z, w2.x, acc[r][0]);
            acc[r][1] = fmaf(xv.z, w2.y, acc[r][1]);
            acc[r][2] = fmaf(xv.z, w2.z, acc[r][2]);
            acc[r][3] = fmaf(xv.z, w2.w, acc[r][3]);
            acc[r][0] = fmaf(xv.w, w3.x, acc[r][0]);
            acc[r][1] = fmaf(xv.w, w3.y, acc[r][1]);
            acc[r][2] = fmaf(xv.w, w3.z, acc[r][2]);
            acc[r][3] = fmaf(xv.w, w3.w, acc[r][3]);
        }
    }
    // epilogue: cols 4tx..4tx+3 -> packed bf16 pairs at hb[row*64 + 2tx], uint2 store
#pragma unroll
    for (int r = 0; r < 4; r++) {
        int gr = row0 + r0 + r;
        if (gr < n) {
            uint2 p;
            p.x = pack_bf16(acc[r][0], acc[r][1]);
            p.y = pack_bf16(acc[r][2], acc[r][3]);
            *(uint2*)&hb[(size_t)gr * (D / 2) + tx * 2] = p;
        }
    }
}

// ---------- Aggregation + bias + relu (bf16 gather, fp32 accumulate/output) ----------
// out[d] = relu( dinv[d] * sum_{e->d} dinv[s]*h[s] + dinv[d]^2 * h[d] + b )
// 1 wave per node, 64 lanes x (2 bf16) = coalesced 256 B gather per edge.

static __global__ __launch_bounds__(256) void agg_k(const unsigned int* __restrict__ hb,
                                                    const float* __restrict__ dinv,
                                                    const int* __restrict__ rowptr,
                                                    const int* __restrict__ csr,
                                                    const float* __restrict__ b,
                                                    float* __restrict__ out, int n) {
    int node = blockIdx.x * 4 + (threadIdx.x >> 6);
    if (node >= n) return;
    int lane = threadIdx.x & 63;
    int beg = rowptr[node], end = rowptr[node + 1];
    float ax = 0.f, ay = 0.f;
    int e = beg;
    for (; e + 3 < end; e += 4) {          // 4-edge unroll for MLP
        int s0 = csr[e], s1 = csr[e + 1], s2 = csr[e + 2], s3 = csr[e + 3];
        float d0 = dinv[s0], d1 = dinv[s1], d2 = dinv[s2], d3 = dinv[s3];
        unsigned int v0 = hb[(size_t)s0 * (D / 2) + lane];
        unsigned int v1 = hb[(size_t)s1 * (D / 2) + lane];
        unsigned int v2 = hb[(size_t)s2 * (D / 2) + lane];
        unsigned int v3 = hb[(size_t)s3 * (D / 2) + lane];
        ax = fmaf(d0, bf16_lo(v0), ax); ay = fmaf(d0, bf16_hi(v0), ay);
        ax = fmaf(d1, bf16_lo(v1), ax); ay = fmaf(d1, bf16_hi(v1), ay);
        ax = fmaf(d2, bf16_lo(v2), ax); ay = fmaf(d2, bf16_hi(v2), ay);
        ax = fmaf(d3, bf16_lo(v3), ax); ay = fmaf(d3, bf16_hi(v3), ay);
    }
    for (; e < end; e++) {
        int s0 = csr[e];
        float d0 = dinv[s0];
        unsigned int v0 = hb[(size_t)s0 * (D / 2) + lane];
        ax = fmaf(d0, bf16_lo(v0), ax); ay = fmaf(d0, bf16_hi(v0), ay);
    }
    float di = dinv[node];
    unsigned int hv = hb[(size_t)node * (D / 2) + lane];
    float2 bb = *(const float2*)&b[lane * 2];
    float ox = fmaf(di, ax, di * di * bf16_lo(hv)) + bb.x;
    float oy = fmaf(di, ay, di * di * bf16_hi(hv)) + bb.y;
    *(float2*)&out[(size_t)node * D + lane * 2] = make_float2(fmaxf(ox, 0.f), fmaxf(oy, 0.f));
}

// ---------- Global mean pool (batch is sorted) ----------

static __global__ __launch_bounds__(256) void pool_k(const float* __restrict__ x,
                                                     const int* __restrict__ batch, int n,
                                                     float* __restrict__ pooled) {
    int g = blockIdx.x;
    int f = threadIdx.x & 127;
    int half = threadIdx.x >> 7;
    int lo = 0, hi = n;
    while (lo < hi) { int m = (lo + hi) >> 1; if (batch[m] < g) lo = m + 1; else hi = m; }
    int start = lo;
    hi = n;
    while (lo < hi) { int m = (lo + hi) >> 1; if (batch[m] < g + 1) lo = m + 1; else hi = m; }
    int end = lo;
    float s = 0.f;
    for (int r = start + half; r < end; r += 2) s += x[(size_t)r * D + f];
    __shared__ float red[256];
    red[threadIdx.x] = s;
    __syncthreads();
    if (half == 0) {
        float tot = red[f] + red[f + 128];
        float c = (float)(end - start);
        pooled[(size_t)g * D + f] = tot / fmaxf(c, 1.0f);
    }
}

// ---------- Classifier: out = relu(pooled@Wc + bc) @ Wo + bo ----------

static __global__ __launch_bounds__(64) void cls_k(const float* __restrict__ pooled,
                                                   const float* __restrict__ Wc,
                                                   const float* __restrict__ bc,
                                                   const float* __restrict__ Wo,
                                                   const float* __restrict__ bo,
                                                   float* __restrict__ out) {
    int g = blockIdx.x;
    int t = threadIdx.x;   // 0..63 -> hidden unit
    __shared__ float p[D];
    p[t] = pooled[(size_t)g * D + t];
    p[t + 64] = pooled[(size_t)g * D + 64 + t];
    __syncthreads();
    float z = bc[t];
    for (int k = 0; k < D; k++) z = fmaf(p[k], Wc[k * H + t], z);
    z = fmaxf(z, 0.f);
    float v = z * Wo[t];
    for (int off = 32; off > 0; off >>= 1) v += __shfl_down(v, off);
    if (t == 0) out[g] = v + bo[0];
}

// ---------- Orchestration ----------

extern "C" void kernel_launch(void* const* d_in, const int* in_sizes, int n_in,
                              void* d_out, int out_size, void* d_ws, size_t ws_size,
                              hipStream_t stream) {
    const float* x     = (const float*)d_in[0];
    const int*   ei    = (const int*)d_in[1];
    const int*   batch = (const int*)d_in[2];
    const float* W1 = (const float*)d_in[3];
    const float* b1 = (const float*)d_in[4];
    const float* W2 = (const float*)d_in[5];
    const float* b2 = (const float*)d_in[6];
    const float* W3 = (const float*)d_in[7];
    const float* b3 = (const float*)d_in[8];
    const float* Wc = (const float*)d_in[9];
    const float* bc = (const float*)d_in[10];
    const float* Wo = (const float*)d_in[11];
    const float* bo = (const float*)d_in[12];

    const int n = in_sizes[0] / D;
    const int E = in_sizes[1] / 2;
    const int G = out_size;

    char* ws = (char*)d_ws;
    size_t off = 0;
    auto alloc = [&](size_t bytes) -> void* {
        void* p = ws + off;
        off = (off + bytes + 255) & ~(size_t)255;
        return p;
    };
    int*   cnt     = (int*)alloc((size_t)n * 4);
    int*   cursor  = (int*)alloc((size_t)n * 4);
    int*   rowptr  = (int*)alloc((size_t)(n + 1) * 4);
    int*   bsum    = (int*)alloc(1024);
    float* dinv    = (float*)alloc((size_t)n * 4);
    int*   csr_src = (int*)alloc((size_t)E * 4);
    unsigned int* hbuf = (unsigned int*)alloc((size_t)n * (D / 2) * 4);  // packed bf16
    float* xbuf    = (float*)alloc((size_t)n * D * 4);
    float* pooled  = (float*)alloc((size_t)G * D * 4);
    (void)ws_size; (void)n_in;

    hipMemsetAsync(cnt, 0, (size_t)n * 4, stream);
    hipMemsetAsync(cursor, 0, (size_t)n * 4, stream);

    const int TB = 256;
    const int nb = (n + 255) / 256;

    hist_k<<<(E + TB - 1) / TB, TB, 0, stream>>>(ei, E, cnt);
    dinv_k<<<(n + TB - 1) / TB, TB, 0, stream>>>(cnt, dinv, n);
    scanA_k<<<nb, 256, 0, stream>>>(cnt, n, bsum);
    scanB_k<<<1, 64, 0, stream>>>(bsum, nb);
    scanC_k<<<nb, 256, 0, stream>>>(cnt, n, bsum, rowptr);
    fill_k<<<(E + TB - 1) / TB, TB, 0, stream>>>(ei, E, rowptr, cursor, csr_src);

    const int gemm_blocks = (n + 31) / 32;
    const int agg_blocks  = (n + 3) / 4;

    // layer 1
    gemm_k<<<gemm_blocks, 256, 0, stream>>>(x, W1, hbuf, n);
    agg_k<<<agg_blocks, 256, 0, stream>>>(hbuf, dinv, rowptr, csr_src, b1, xbuf, n);
    // layer 2
    gemm_k<<<gemm_blocks, 256, 0, stream>>>(xbuf, W2, hbuf, n);
    agg_k<<<agg_blocks, 256, 0, stream>>>(hbuf, dinv, rowptr, csr_src, b2, xbuf, n);
    // layer 3
    gemm_k<<<gemm_blocks, 256, 0, stream>>>(xbuf, W3, hbuf, n);
    agg_k<<<agg_blocks, 256, 0, stream>>>(hbuf, dinv, rowptr, csr_src, b3, xbuf, n);

    pool_k<<<G, 256, 0, stream>>>(xbuf, batch, n, pooled);
    cls_k<<<G, 64, 0, stream>>>(pooled, Wc, bc, Wo, bo, (float*)d_out);
}

// Round 3
// 450.160 us; speedup vs baseline: 1.3435x; 1.0344x over previous
//
#include <hip/hip_runtime.h>

#define D 128   // feature dim
#define H 64    // hidden dim of classifier

// ---------- bf16 helpers (bit-level, RNE) ----------

__device__ __forceinline__ unsigned int bf16_rne(float f) {
    unsigned int u = __float_as_uint(f);
    u += 0x7fffu + ((u >> 16) & 1u);
    return u >> 16;
}
__device__ __forceinline__ unsigned int pack_bf16(float a, float b) {
    return bf16_rne(a) | (bf16_rne(b) << 16);
}
__device__ __forceinline__ float bf16_lo(unsigned int u) { return __uint_as_float(u << 16); }
__device__ __forceinline__ float bf16_hi(unsigned int u) { return __uint_as_float(u & 0xffff0000u); }

// ---------- CSR construction ----------

static __global__ void hist_k(const int* __restrict__ ei, int E, int* __restrict__ cnt) {
    int e = blockIdx.x * blockDim.x + threadIdx.x;
    if (e < E) atomicAdd(&cnt[ei[E + e]], 1);   // dst row of edge_index
}

static __global__ void dinv_k(const int* __restrict__ cnt, float* __restrict__ dinv, int n) {
    int i = blockIdx.x * blockDim.x + threadIdx.x;
    if (i < n) dinv[i] = rsqrtf((float)cnt[i] + 1.0f);   // +1 for self loop; deg >= 1 always
}

static __global__ void scanA_k(const int* __restrict__ cnt, int n, int* __restrict__ bsum) {
    __shared__ int s[256];
    int i = blockIdx.x * 256 + threadIdx.x;
    s[threadIdx.x] = (i < n) ? cnt[i] : 0;
    __syncthreads();
    for (int off = 128; off > 0; off >>= 1) {
        if ((int)threadIdx.x < off) s[threadIdx.x] += s[threadIdx.x + off];
        __syncthreads();
    }
    if (threadIdx.x == 0) bsum[blockIdx.x] = s[0];
}

static __global__ void scanB_k(int* __restrict__ bsum, int nb) {
    if (threadIdx.x == 0 && blockIdx.x == 0) {
        int run = 0;
        for (int i = 0; i < nb; i++) { int t = bsum[i]; bsum[i] = run; run += t; }
    }
}

static __global__ void scanC_k(const int* __restrict__ cnt, int n, const int* __restrict__ bsum,
                               int* __restrict__ rowptr) {
    __shared__ int s[256];
    int i = blockIdx.x * 256 + threadIdx.x;
    int v = (i < n) ? cnt[i] : 0;
    s[threadIdx.x] = v;
    __syncthreads();
    for (int off = 1; off < 256; off <<= 1) {       // inclusive Hillis-Steele
        int t = ((int)threadIdx.x >= off) ? s[threadIdx.x - off] : 0;
        __syncthreads();
        s[threadIdx.x] += t;
        __syncthreads();
    }
    if (i < n) {
        int excl = bsum[blockIdx.x] + s[threadIdx.x] - v;
        rowptr[i] = excl;
        if (i == n - 1) rowptr[n] = excl + v;
    }
}

static __global__ void fill_k(const int* __restrict__ ei, int E, const int* __restrict__ rowptr,
                              int* __restrict__ cursor, int* __restrict__ csr_src) {
    int e = blockIdx.x * blockDim.x + threadIdx.x;
    if (e < E) {
        int s = ei[e];
        int d = ei[E + e];
        int p = atomicAdd(&cursor[d], 1);
        csr_src[rowptr[d] + p] = s;
    }
}

// ---------- GEMM: h_bf16 = bf16(x @ W) ----------
// 64-row x 128-col tile, 256 threads, K chunked by 32.
// LDS = W-chunk [32][128] (16 KB) + TRANSPOSED x-tile [k][row] (8 KB) = 24 KB
//   -> ~6 blocks/CU by LDS; grid (782) fully co-resident (~3 blocks/CU, 3 waves/SIMD).
// Thread = 8 rows x 4 cols; per k: 1 b128 W-read + 2 broadcast b128 x-reads for 32 FMAs.

static __global__ __launch_bounds__(256) void gemm_k(const float* __restrict__ x,
                                                     const float* __restrict__ W,
                                                     unsigned int* __restrict__ hb, int n) {
    __shared__ float Ws[32 * D];     // [kk][col] 16 KB
    __shared__ float xT[32 * 64];    // [kk][row]  8 KB
    const int tid = threadIdx.x;
    const int row0 = blockIdx.x * 64;
    const int tx = tid & 31;        // cols 4*tx .. 4*tx+3
    const int ty = tid >> 5;        // 0..7 -> rows 8*ty .. 8*ty+7
    // staging assignment: row sr, k-offsets sk..sk+3 and sk+16..sk+19
    const int sr = tid & 63;
    const int sk = (tid >> 6) * 4;  // 0,4,8,12
    const int gr = row0 + sr;

    float acc[8][4];
#pragma unroll
    for (int r = 0; r < 8; r++)
#pragma unroll
        for (int c = 0; c < 4; c++) acc[r][c] = 0.f;

    for (int kc = 0; kc < D; kc += 32) {
        // load next chunk into registers (no LDS dependency yet)
        float4 wreg[4];
#pragma unroll
        for (int i = 0; i < 4; i++)
            wreg[i] = ((const float4*)(W + kc * D))[tid + 256 * i];
        float4 v0 = make_float4(0.f, 0.f, 0.f, 0.f), v1 = v0;
        if (gr < n) {
            v0 = *(const float4*)&x[(size_t)gr * D + kc + sk];
            v1 = *(const float4*)&x[(size_t)gr * D + kc + sk + 16];
        }
        __syncthreads();   // previous chunk's compute done
#pragma unroll
        for (int i = 0; i < 4; i++)
            ((float4*)Ws)[tid + 256 * i] = wreg[i];
        xT[(sk + 0) * 64 + sr] = v0.x;
        xT[(sk + 1) * 64 + sr] = v0.y;
        xT[(sk + 2) * 64 + sr] = v0.z;
        xT[(sk + 3) * 64 + sr] = v0.w;
        xT[(sk + 16) * 64 + sr] = v1.x;
        xT[(sk + 17) * 64 + sr] = v1.y;
        xT[(sk + 18) * 64 + sr] = v1.z;
        xT[(sk + 19) * 64 + sr] = v1.w;
        __syncthreads();

#pragma unroll 8
        for (int k = 0; k < 32; k++) {
            float4 w  = *(const float4*)&Ws[k * D + tx * 4];
            float4 xa = *(const float4*)&xT[k * 64 + ty * 8];
            float4 xb = *(const float4*)&xT[k * 64 + ty * 8 + 4];
            acc[0][0] = fmaf(xa.x, w.x, acc[0][0]); acc[0][1] = fmaf(xa.x, w.y, acc[0][1]);
            acc[0][2] = fmaf(xa.x, w.z, acc[0][2]); acc[0][3] = fmaf(xa.x, w.w, acc[0][3]);
            acc[1][0] = fmaf(xa.y, w.x, acc[1][0]); acc[1][1] = fmaf(xa.y, w.y, acc[1][1]);
            acc[1][2] = fmaf(xa.y, w.z, acc[1][2]); acc[1][3] = fmaf(xa.y, w.w, acc[1][3]);
            acc[2][0] = fmaf(xa.z, w.x, acc[2][0]); acc[2][1] = fmaf(xa.z, w.y, acc[2][1]);
            acc[2][2] = fmaf(xa.z, w.z, acc[2][2]); acc[2][3] = fmaf(xa.z, w.w, acc[2][3]);
            acc[3][0] = fmaf(xa.w, w.x, acc[3][0]); acc[3][1] = fmaf(xa.w, w.y, acc[3][1]);
            acc[3][2] = fmaf(xa.w, w.z, acc[3][2]); acc[3][3] = fmaf(xa.w, w.w, acc[3][3]);
            acc[4][0] = fmaf(xb.x, w.x, acc[4][0]); acc[4][1] = fmaf(xb.x, w.y, acc[4][1]);
            acc[4][2] = fmaf(xb.x, w.z, acc[4][2]); acc[4][3] = fmaf(xb.x, w.w, acc[4][3]);
            acc[5][0] = fmaf(xb.y, w.x, acc[5][0]); acc[5][1] = fmaf(xb.y, w.y, acc[5][1]);
            acc[5][2] = fmaf(xb.y, w.z, acc[5][2]); acc[5][3] = fmaf(xb.y, w.w, acc[5][3]);
            acc[6][0] = fmaf(xb.z, w.x, acc[6][0]); acc[6][1] = fmaf(xb.z, w.y, acc[6][1]);
            acc[6][2] = fmaf(xb.z, w.z, acc[6][2]); acc[6][3] = fmaf(xb.z, w.w, acc[6][3]);
            acc[7][0] = fmaf(xb.w, w.x, acc[7][0]); acc[7][1] = fmaf(xb.w, w.y, acc[7][1]);
            acc[7][2] = fmaf(xb.w, w.z, acc[7][2]); acc[7][3] = fmaf(xb.w, w.w, acc[7][3]);
        }
    }
    // epilogue: pack bf16 pairs, uint2 store per row
#pragma unroll
    for (int r = 0; r < 8; r++) {
        int grr = row0 + ty * 8 + r;
        if (grr < n) {
            uint2 p;
            p.x = pack_bf16(acc[r][0], acc[r][1]);
            p.y = pack_bf16(acc[r][2], acc[r][3]);
            *(uint2*)&hb[(size_t)grr * (D / 2) + tx * 2] = p;
        }
    }
}

// ---------- Aggregation + bias + relu (bf16 gather, fp32 accumulate/output) ----------

static __global__ __launch_bounds__(256) void agg_k(const unsigned int* __restrict__ hb,
                                                    const float* __restrict__ dinv,
                                                    const int* __restrict__ rowptr,
                                                    const int* __restrict__ csr,
                                                    const float* __restrict__ b,
                                                    float* __restrict__ out, int n) {
    int node = blockIdx.x * 4 + (threadIdx.x >> 6);
    if (node >= n) return;
    int lane = threadIdx.x & 63;
    int beg = rowptr[node], end = rowptr[node + 1];
    float ax = 0.f, ay = 0.f;
    int e = beg;
    for (; e + 3 < end; e += 4) {          // 4-edge unroll for MLP
        int s0 = csr[e], s1 = csr[e + 1], s2 = csr[e + 2], s3 = csr[e + 3];
        float d0 = dinv[s0], d1 = dinv[s1], d2 = dinv[s2], d3 = dinv[s3];
        unsigned int v0 = hb[(size_t)s0 * (D / 2) + lane];
        unsigned int v1 = hb[(size_t)s1 * (D / 2) + lane];
        unsigned int v2 = hb[(size_t)s2 * (D / 2) + lane];
        unsigned int v3 = hb[(size_t)s3 * (D / 2) + lane];
        ax = fmaf(d0, bf16_lo(v0), ax); ay = fmaf(d0, bf16_hi(v0), ay);
        ax = fmaf(d1, bf16_lo(v1), ax); ay = fmaf(d1, bf16_hi(v1), ay);
        ax = fmaf(d2, bf16_lo(v2), ax); ay = fmaf(d2, bf16_hi(v2), ay);
        ax = fmaf(d3, bf16_lo(v3), ax); ay = fmaf(d3, bf16_hi(v3), ay);
    }
    for (; e < end; e++) {
        int s0 = csr[e];
        float d0 = dinv[s0];
        unsigned int v0 = hb[(size_t)s0 * (D / 2) + lane];
        ax = fmaf(d0, bf16_lo(v0), ax); ay = fmaf(d0, bf16_hi(v0), ay);
    }
    float di = dinv[node];
    unsigned int hv = hb[(size_t)node * (D / 2) + lane];
    float2 bb = *(const float2*)&b[lane * 2];
    float ox = fmaf(di, ax, di * di * bf16_lo(hv)) + bb.x;
    float oy = fmaf(di, ay, di * di * bf16_hi(hv)) + bb.y;
    *(float2*)&out[(size_t)node * D + lane * 2] = make_float2(fmaxf(ox, 0.f), fmaxf(oy, 0.f));
}

// ---------- Global mean pool (batch is sorted) ----------

static __global__ __launch_bounds__(256) void pool_k(const float* __restrict__ x,
                                                     const int* __restrict__ batch, int n,
                                                     float* __restrict__ pooled) {
    int g = blockIdx.x;
    int f = threadIdx.x & 127;
    int half = threadIdx.x >> 7;
    int lo = 0, hi = n;
    while (lo < hi) { int m = (lo + hi) >> 1; if (batch[m] < g) lo = m + 1; else hi = m; }
    int start = lo;
    hi = n;
    while (lo < hi) { int m = (lo + hi) >> 1; if (batch[m] < g + 1) lo = m + 1; else hi = m; }
    int end = lo;
    float s = 0.f;
    for (int r = start + half; r < end; r += 2) s += x[(size_t)r * D + f];
    __shared__ float red[256];
    red[threadIdx.x] = s;
    __syncthreads();
    if (half == 0) {
        float tot = red[f] + red[f + 128];
        float c = (float)(end - start);
        pooled[(size_t)g * D + f] = tot / fmaxf(c, 1.0f);
    }
}

// ---------- Classifier: out = relu(pooled@Wc + bc) @ Wo + bo ----------

static __global__ __launch_bounds__(64) void cls_k(const float* __restrict__ pooled,
                                                   const float* __restrict__ Wc,
                                                   const float* __restrict__ bc,
                                                   const float* __restrict__ Wo,
                                                   const float* __restrict__ bo,
                                                   float* __restrict__ out) {
    int g = blockIdx.x;
    int t = threadIdx.x;   // 0..63 -> hidden unit
    __shared__ float p[D];
    p[t] = pooled[(size_t)g * D + t];
    p[t + 64] = pooled[(size_t)g * D + 64 + t];
    __syncthreads();
    float z = bc[t];
    for (int k = 0; k < D; k++) z = fmaf(p[k], Wc[k * H + t], z);
    z = fmaxf(z, 0.f);
    float v = z * Wo[t];
    for (int off = 32; off > 0; off >>= 1) v += __shfl_down(v, off);
    if (t == 0) out[g] = v + bo[0];
}

// ---------- Orchestration ----------

extern "C" void kernel_launch(void* const* d_in, const int* in_sizes, int n_in,
                              void* d_out, int out_size, void* d_ws, size_t ws_size,
                              hipStream_t stream) {
    const float* x     = (const float*)d_in[0];
    const int*   ei    = (const int*)d_in[1];
    const int*   batch = (const int*)d_in[2];
    const float* W1 = (const float*)d_in[3];
    const float* b1 = (const float*)d_in[4];
    const float* W2 = (const float*)d_in[5];
    const float* b2 = (const float*)d_in[6];
    const float* W3 = (const float*)d_in[7];
    const float* b3 = (const float*)d_in[8];
    const float* Wc = (const float*)d_in[9];
    const float* bc = (const float*)d_in[10];
    const float* Wo = (const float*)d_in[11];
    const float* bo = (const float*)d_in[12];

    const int n = in_sizes[0] / D;
    const int E = in_sizes[1] / 2;
    const int G = out_size;

    char* ws = (char*)d_ws;
    size_t off = 0;
    auto alloc = [&](size_t bytes) -> void* {
        void* p = ws + off;
        off = (off + bytes + 255) & ~(size_t)255;
        return p;
    };
    int*   cnt     = (int*)alloc((size_t)n * 4);
    int*   cursor  = (int*)alloc((size_t)n * 4);
    int*   rowptr  = (int*)alloc((size_t)(n + 1) * 4);
    int*   bsum    = (int*)alloc(1024);
    float* dinv    = (float*)alloc((size_t)n * 4);
    int*   csr_src = (int*)alloc((size_t)E * 4);
    unsigned int* hbuf = (unsigned int*)alloc((size_t)n * (D / 2) * 4);  // packed bf16
    float* xbuf    = (float*)alloc((size_t)n * D * 4);
    float* pooled  = (float*)alloc((size_t)G * D * 4);
    (void)ws_size; (void)n_in;

    hipMemsetAsync(cnt, 0, (size_t)n * 4, stream);
    hipMemsetAsync(cursor, 0, (size_t)n * 4, stream);

    const int TB = 256;
    const int nb = (n + 255) / 256;

    hist_k<<<(E + TB - 1) / TB, TB, 0, stream>>>(ei, E, cnt);
    dinv_k<<<(n + TB - 1) / TB, TB, 0, stream>>>(cnt, dinv, n);
    scanA_k<<<nb, 256, 0, stream>>>(cnt, n, bsum);
    scanB_k<<<1, 64, 0, stream>>>(bsum, nb);
    scanC_k<<<nb, 256, 0, stream>>>(cnt, n, bsum, rowptr);
    fill_k<<<(E + TB - 1) / TB, TB, 0, stream>>>(ei, E, rowptr, cursor, csr_src);

    const int gemm_blocks = (n + 63) / 64;
    const int agg_blocks  = (n + 3) / 4;

    // layer 1
    gemm_k<<<gemm_blocks, 256, 0, stream>>>(x, W1, hbuf, n);
    agg_k<<<agg_blocks, 256, 0, stream>>>(hbuf, dinv, rowptr, csr_src, b1, xbuf, n);
    // layer 2
    gemm_k<<<gemm_blocks, 256, 0, stream>>>(xbuf, W2, hbuf, n);
    agg_k<<<agg_blocks, 256, 0, stream>>>(hbuf, dinv, rowptr, csr_src, b2, xbuf, n);
    // layer 3
    gemm_k<<<gemm_blocks, 256, 0, stream>>>(xbuf, W3, hbuf, n);
    agg_k<<<agg_blocks, 256, 0, stream>>>(hbuf, dinv, rowptr, csr_src, b3, xbuf, n);

    pool_k<<<G, 256, 0, stream>>>(xbuf, batch, n, pooled);
    cls_k<<<G, 64, 0, stream>>>(pooled, Wc, bc, Wo, bo, (float*)d_out);
}